// Round 6
// baseline (522.315 us; speedup 1.0000x reference)
//
#include <hip/hip_runtime.h>
#include <hip/hip_bf16.h>
#include <stdint.h>

// Problem constants
#define B_ 64
#define T_ 512
#define H_ 256
#define D_ 512
#define MS_ 64
#define ML_ 8
#define NST_ 64

typedef unsigned short u16;
typedef unsigned int u32;
typedef __bf16 bf8 __attribute__((ext_vector_type(8)));
typedef float f4 __attribute__((ext_vector_type(4)));

__device__ __forceinline__ u16 f2bf(float f) {
    u32 u = __builtin_bit_cast(u32, f);
    u += 0x7fffu + ((u >> 16) & 1u);   // round-to-nearest-even
    return (u16)(u >> 16);
}
__device__ __forceinline__ float bf2f(u16 v) {
    u32 u = ((u32)v) << 16;
    return __builtin_bit_cast(float, u);
}
__device__ __forceinline__ float sigm(float x) { return 1.f / (1.f + __expf(-x)); }

// ---------------- weight packing ----------------
// wih2[2048][512] bf16 : rows 0..1023 = W_ih_f, 1024..2047 = W_ih_b
// whh2[2][1024][256] bf16
__global__ __launch_bounds__(256) void build_w2(const float* __restrict__ wihf,
                                                const float* __restrict__ whhf,
                                                const float* __restrict__ wihb,
                                                const float* __restrict__ whhb,
                                                u16* __restrict__ wih2,
                                                u16* __restrict__ whh2) {
    int i = blockIdx.x * 256 + threadIdx.x;
    if (i < 1048576) {
        int g = i >> 9, k = i & 511;
        float v = (g < 1024) ? wihf[g * 512 + k] : wihb[(g - 1024) * 512 + k];
        wih2[i] = f2bf(v);
    } else if (i < 1572864) {
        int j = i - 1048576;
        int dir = j >> 18;
        int r = j & 262143;
        int g = r >> 8, k = r & 255;
        float v = dir ? whhb[g * 256 + k] : whhf[g * 256 + k];
        whh2[j] = f2bf(v);
    }
}

__global__ __launch_bounds__(256) void zero_ws(uint4* __restrict__ dst, int n4) {
    int i = blockIdx.x * 256 + threadIdx.x;
    if (i < n4) { uint4 z = {0u, 0u, 0u, 0u}; dst[i] = z; }
}

// ---------------- span packing (parallel, 1 block/row, 1 thread/token) -------
__global__ __launch_bounds__(512) void pack_spans2(const int* __restrict__ bio,
                                                   int* __restrict__ tok,
                                                   int* __restrict__ lenb) {
    __shared__ int wsum[8];
    __shared__ int start_s[64];
    __shared__ int len_s[64];
    int b = blockIdx.x;
    int t = threadIdx.x;
    int lane = t & 63, w = t >> 6;
    int v = bio[b * T_ + t];
    int bm = (v == 1);
    int im = (v == 2);
    if (t < 64) len_s[t] = 0;

    int x = bm;
#pragma unroll
    for (int off = 1; off < 64; off <<= 1) {
        int y = __shfl_up(x, off, 64);
        if (lane >= off) x += y;
    }
    if (lane == 63) wsum[w] = x;
    __syncthreads();
    int wof = 0;
    for (int i = 0; i < w; ++i) wof += wsum[i];
    int sid = x + wof - 1;
    int valid = ((bm | im) && sid >= 0) ? 1 : 0;
    __syncthreads();

    x = valid;
#pragma unroll
    for (int off = 1; off < 64; off <<= 1) {
        int y = __shfl_up(x, off, 64);
        if (lane >= off) x += y;
    }
    if (lane == 63) wsum[w] = x;
    __syncthreads();
    wof = 0;
    for (int i = 0; i < w; ++i) wof += wsum[i];
    int cs = x + wof;

    if (bm && sid < MS_) start_s[sid] = cs;
    __syncthreads();

    if (valid && sid < MS_) {
        int rank = cs - start_s[sid];
        if (rank < ML_) {
            tok[(b * MS_ + sid) * ML_ + rank] = t;
            atomicAdd(&len_s[sid], 1);
        }
    }
    __syncthreads();
    if (t < 64) lenb[b * MS_ + t] = len_s[t];
}

// ---------------- aux lists: valid (span,rank) rows + length-sorted span order
__global__ __launch_bounds__(256) void build_aux(const int* __restrict__ lenb,
                                                 int* __restrict__ vrows,
                                                 int* __restrict__ sorder,
                                                 int* __restrict__ counts) {
    __shared__ int wsum[4];
    __shared__ int gbase;
    int tid = threadIdx.x;
    int lane = tid & 63, w = tid >> 6;
    int len[16];
#pragma unroll
    for (int i = 0; i < 16; ++i) len[i] = lenb[tid * 16 + i];

    // valid rows (span*8 + rank for rank < len)
    int cnt = 0;
#pragma unroll
    for (int i = 0; i < 16; ++i) cnt += len[i];
    int x = cnt;
#pragma unroll
    for (int off = 1; off < 64; off <<= 1) {
        int y = __shfl_up(x, off, 64);
        if (lane >= off) x += y;
    }
    if (lane == 63) wsum[w] = x;
    __syncthreads();
    int wof = 0;
    for (int i = 0; i < w; ++i) wof += wsum[i];
    int pos = wof + x - cnt;
#pragma unroll
    for (int i = 0; i < 16; ++i)
        for (int r = 0; r < len[i]; ++r) vrows[pos++] = (tid * 16 + i) * 8 + r;
    if (tid == 255) counts[0] = pos;   // nv
    __syncthreads();

    // sorder: spans bucketed by descending length (stable)
    if (tid == 0) gbase = 0;
    __syncthreads();
    for (int L = 8; L >= 0; --L) {
        int c = 0;
#pragma unroll
        for (int i = 0; i < 16; ++i) c += (len[i] == L) ? 1 : 0;
        x = c;
#pragma unroll
        for (int off = 1; off < 64; off <<= 1) {
            int y = __shfl_up(x, off, 64);
            if (lane >= off) x += y;
        }
        if (lane == 63) wsum[w] = x;
        __syncthreads();
        wof = 0;
        for (int i = 0; i < w; ++i) wof += wsum[i];
        int p2 = gbase + wof + x - c;
#pragma unroll
        for (int i = 0; i < 16; ++i)
            if (len[i] == L) sorder[p2++] = tid * 16 + i;
        __syncthreads();
        if (tid == 255) gbase = p2;
        __syncthreads();
    }
}

// Gather-convert used tokens: xg[span*8+rank][512] bf16.
__global__ __launch_bounds__(64) void conv_gather(const float* __restrict__ repr,
                                                  const int* __restrict__ tok,
                                                  const int* __restrict__ lenb,
                                                  u16* __restrict__ xg) {
    int sr = blockIdx.x;
    int span = sr >> 3, rank = sr & 7;
    if (rank >= lenb[span]) return;
    int t = tok[sr];
    int b = span >> 6;
    const float4* src = (const float4*)(repr + (size_t)(b * T_ + t) * D_);
    ushort4* dst = (ushort4*)(xg + (size_t)sr * D_);
    int i = threadIdx.x;
    float4 v0 = src[i * 2], v1 = src[i * 2 + 1];
    ushort4 o0, o1;
    o0.x = f2bf(v0.x); o0.y = f2bf(v0.y); o0.z = f2bf(v0.z); o0.w = f2bf(v0.w);
    o1.x = f2bf(v1.x); o1.y = f2bf(v1.y); o1.z = f2bf(v1.z); o1.w = f2bf(v1.w);
    dst[i * 2] = o0; dst[i * 2 + 1] = o1;
}

// ---------------- input GEMM: xw[sr][2048] = x[sr] @ wih2^T + bias (bf16 out)
__global__ __launch_bounds__(256) void xw_gemm(const u16* __restrict__ xg,
                                               const u16* __restrict__ wih2,
                                               const float* __restrict__ b_f,
                                               const float* __restrict__ b_b,
                                               const int* __restrict__ vrows,
                                               const int* __restrict__ counts,
                                               u16* __restrict__ xw) {
    int nv = counts[0];
    int base = blockIdx.y * 128;
    if (base >= nv) return;
    __shared__ int varr[128];
    __shared__ u16 As[128 * 72];
    __shared__ u16 Bs[128 * 72];
    int tid = threadIdx.x;
    if (tid < 128) varr[tid] = (base + tid < nv) ? vrows[base + tid] : -1;
    __syncthreads();
    int lane = tid & 63, wv = tid >> 6;
    int mr = lane & 15, q = lane >> 4, q8 = q * 8;
    int m0 = (wv >> 1) * 64, n0 = (wv & 1) * 64;
    int bx = blockIdx.x;

    f4 acc[4][4];
    f4 zed = {0.f, 0.f, 0.f, 0.f};
#pragma unroll
    for (int i = 0; i < 4; ++i)
#pragma unroll
        for (int j = 0; j < 4; ++j) acc[i][j] = zed;

    for (int kt = 0; kt < 8; ++kt) {
#pragma unroll
        for (int i = 0; i < 4; ++i) {
            int cch = tid + i * 256;
            int row = cch >> 3, cc = (cch & 7) * 8;
            int vr = varr[row];
            uint4 v = {0u, 0u, 0u, 0u};
            if (vr >= 0) v = *(const uint4*)(xg + (size_t)vr * 512 + kt * 64 + cc);
            *(uint4*)&As[row * 72 + cc] = v;
            uint4 wv4 = *(const uint4*)(wih2 + (size_t)(bx * 128 + row) * 512 + kt * 64 + cc);
            *(uint4*)&Bs[row * 72 + cc] = wv4;
        }
        __syncthreads();
#pragma unroll
        for (int kk = 0; kk < 64; kk += 32) {
            bf8 af[4], bgv[4];
#pragma unroll
            for (int i = 0; i < 4; ++i) af[i] = *(const bf8*)&As[(m0 + i * 16 + mr) * 72 + kk + q8];
#pragma unroll
            for (int j = 0; j < 4; ++j) bgv[j] = *(const bf8*)&Bs[(n0 + j * 16 + mr) * 72 + kk + q8];
#pragma unroll
            for (int i = 0; i < 4; ++i)
#pragma unroll
                for (int j = 0; j < 4; ++j)
                    acc[i][j] = __builtin_amdgcn_mfma_f32_16x16x32_bf16(af[i], bgv[j], acc[i][j], 0, 0, 0);
        }
        __syncthreads();
    }
#pragma unroll
    for (int j = 0; j < 4; ++j) {
        int n = bx * 128 + n0 + j * 16 + mr;
        float bias = (n < 1024) ? b_f[n] : b_b[n - 1024];
#pragma unroll
        for (int i = 0; i < 4; ++i)
#pragma unroll
            for (int r = 0; r < 4; ++r) {
                int m = m0 + i * 16 + q * 4 + r;
                int vr = varr[m];
                if (vr >= 0) xw[(size_t)vr * 2048 + n] = f2bf(acc[i][j][r] + bias);
            }
    }
}

// ---------------- fused LSTM recurrence, register-budgeted ----------------
// Block = 4 waves / 16 spans (length-sorted slice) / one dir. Wave wv owns
// hidden strip [wv*64, wv*64+64). Per step: bg = h B-frags from LDS (dbuf),
// W_hh A-frags streamed from L2, cell math on MFMA accumulators.
// Per-lane state: bg 32 + c 16 + pool 16 + transients -> ~150 VGPR, no spill.
__global__ __launch_bounds__(256, 2) void lstm_fused3(const u16* __restrict__ whh2,
                                                      const u16* __restrict__ xw,
                                                      const int* __restrict__ sorder,
                                                      const int* __restrict__ lenb,
                                                      float* __restrict__ pooled) {
    __shared__ u16 Hs[2][16 * 264];
    __shared__ int sl[16], ll[16];
    int bid = blockIdx.x;
    int dir = bid >> 8, slice = bid & 255;
    int tid = threadIdx.x;
    if (tid < 16) {
        int s = sorder[slice * 16 + tid];
        sl[tid] = s;
        ll[tid] = lenb[s];
    }
    for (int i = tid; i < 16 * 264 / 2; i += 256) ((u32*)Hs[0])[i] = 0u;
    __syncthreads();
    int maxP = ll[0];              // sorted descending within slice
    if (maxP == 0) return;

    int wv = tid >> 6;             // hidden strip [wv*64, wv*64+64)
    int lane = tid & 63;
    int mr = lane & 15, q = lane >> 4, q8 = q * 8;
    int w64 = wv * 64;
    const u16* wdir = whh2 + (size_t)dir * 262144;
    int span = sl[mr], len = ll[mr];

    float c[16], pool[16];         // [gt4][r4] for span=mr, hid=w64+gt*16+q*4+r
#pragma unroll
    for (int i = 0; i < 16; ++i) { c[i] = 0.f; pool[i] = 0.f; }

    for (int p = 0; p < maxP; ++p) {
        const u16* hread = Hs[p & 1];
        u16* hwrite = Hs[(p & 1) ^ 1];

        bf8 bg[8];
#pragma unroll
        for (int kk = 0; kk < 8; ++kk)
            bg[kk] = *(const bf8*)&hread[mr * 264 + kk * 32 + q8];

        int rk = dir ? (len - 1 - p) : p;
        rk = rk < 0 ? 0 : (rk > 7 ? 7 : rk);
        const u16* xwp = xw + (size_t)(span * 8 + rk) * 2048 + dir * 1024;
        bool msk = (p < len);

#pragma unroll
        for (int gt = 0; gt < 4; ++gt) {
            f4 acc[4];
            f4 zed = {0.f, 0.f, 0.f, 0.f};
#pragma unroll
            for (int t = 0; t < 4; ++t) acc[t] = zed;
#pragma unroll
            for (int t = 0; t < 4; ++t) {
                const u16* wr = wdir + (size_t)(t * 256 + w64 + gt * 16 + mr) * 256;
                bf8 wf[8];
#pragma unroll
                for (int kk = 0; kk < 8; ++kk)
                    wf[kk] = *(const bf8*)(wr + kk * 32 + q8);
#pragma unroll
                for (int kk = 0; kk < 8; ++kk)
                    acc[t] = __builtin_amdgcn_mfma_f32_16x16x32_bf16(wf[kk], bg[kk], acc[t], 0, 0, 0);
            }
            int col = w64 + gt * 16 + q * 4;
            float xv[4][4];
#pragma unroll
            for (int t = 0; t < 4; ++t) {
                ushort4 uv = *(const ushort4*)(xwp + t * 256 + col);
                xv[t][0] = bf2f(uv.x); xv[t][1] = bf2f(uv.y);
                xv[t][2] = bf2f(uv.z); xv[t][3] = bf2f(uv.w);
            }
            float hv[4];
#pragma unroll
            for (int r = 0; r < 4; ++r) {
                float I = acc[0][r] + xv[0][r];
                float F = acc[1][r] + xv[1][r];
                float G = acc[2][r] + xv[2][r];
                float O = acc[3][r] + xv[3][r];
                int ci = gt * 4 + r;
                float cn = sigm(F) * c[ci] + sigm(I) * tanhf(G);
                c[ci] = cn;
                float h = sigm(O) * tanhf(cn);
                hv[r] = h;
                if (msk) pool[ci] += h;
            }
            u16* hp = &hwrite[mr * 264 + col];
            hp[0] = f2bf(hv[0]); hp[1] = f2bf(hv[1]);
            hp[2] = f2bf(hv[2]); hp[3] = f2bf(hv[3]);
        }
        __syncthreads();
    }

    // pooled store: each (span, dir-half, hid) written by exactly one lane
#pragma unroll
    for (int gt = 0; gt < 4; ++gt) {
        int col = w64 + gt * 16 + q * 4;
        float4 v;
        v.x = pool[gt * 4 + 0];
        v.y = pool[gt * 4 + 1];
        v.z = pool[gt * 4 + 2];
        v.w = pool[gt * 4 + 3];
        *(float4*)(pooled + (size_t)span * 512 + dir * 256 + col) = v;
    }
}

// ---------------- final scores: MFMA GEMM [4096x512] x [512x64] ----------------
__global__ __launch_bounds__(256) void scores_mfma(const float* __restrict__ pooled,
                                                   const float* __restrict__ emb,
                                                   float* __restrict__ out) {
    int g = blockIdx.x;
    int tid = threadIdx.x;
    __shared__ u16 As[64 * 72];
    __shared__ u16 Bs[64 * 72];
    int lane = tid & 63;
    int w16 = (tid >> 6) * 16;
    int mr = lane & 15;
    int q = lane >> 4;
    int q8 = q * 8;

    f4 acc[4];
    f4 zed = {0.f, 0.f, 0.f, 0.f};
#pragma unroll
    for (int i = 0; i < 4; ++i) acc[i] = zed;

    for (int kt = 0; kt < 8; ++kt) {
#pragma unroll
        for (int i = 0; i < 2; ++i) {
            int cch = tid + i * 256;
            int row = cch >> 3;
            int cc = (cch & 7) * 8;
            const float4* a = (const float4*)(pooled + (size_t)(g * 64 + row) * 512 + kt * 64 + cc);
            float4 v0 = a[0], v1 = a[1];
            ushort4 o0, o1;
            o0.x = f2bf(v0.x); o0.y = f2bf(v0.y); o0.z = f2bf(v0.z); o0.w = f2bf(v0.w);
            o1.x = f2bf(v1.x); o1.y = f2bf(v1.y); o1.z = f2bf(v1.z); o1.w = f2bf(v1.w);
            *(ushort4*)&As[row * 72 + cc] = o0;
            *(ushort4*)&As[row * 72 + cc + 4] = o1;
            const float4* b = (const float4*)(emb + (size_t)row * 512 + kt * 64 + cc);
            float4 w0 = b[0], w1 = b[1];
            ushort4 p0, p1;
            p0.x = f2bf(w0.x); p0.y = f2bf(w0.y); p0.z = f2bf(w0.z); p0.w = f2bf(w0.w);
            p1.x = f2bf(w1.x); p1.y = f2bf(w1.y); p1.z = f2bf(w1.z); p1.w = f2bf(w1.w);
            *(ushort4*)&Bs[row * 72 + cc] = p0;
            *(ushort4*)&Bs[row * 72 + cc + 4] = p1;
        }
        __syncthreads();
#pragma unroll
        for (int kk = 0; kk < 64; kk += 32) {
            bf8 af = *(const bf8*)&As[(w16 + mr) * 72 + kk + q8];
#pragma unroll
            for (int nt = 0; nt < 4; ++nt) {
                bf8 bgv = *(const bf8*)&Bs[(nt * 16 + mr) * 72 + kk + q8];
                acc[nt] = __builtin_amdgcn_mfma_f32_16x16x32_bf16(af, bgv, acc[nt], 0, 0, 0);
            }
        }
        __syncthreads();
    }
#pragma unroll
    for (int nt = 0; nt < 4; ++nt)
#pragma unroll
        for (int r = 0; r < 4; ++r) {
            int m = g * 64 + w16 + q * 4 + r;
            int n = nt * 16 + mr;
            out[(size_t)m * 64 + n] = acc[nt][r];
        }
}

// ---------------- launch ----------------

extern "C" void kernel_launch(void* const* d_in, const int* in_sizes, int n_in,
                              void* d_out, int out_size, void* d_ws, size_t ws_size,
                              hipStream_t stream) {
    const float* lstm_repr = (const float*)d_in[0];
    const float* W_ih_f = (const float*)d_in[1];
    const float* W_hh_f = (const float*)d_in[2];
    const float* b_f    = (const float*)d_in[3];
    const float* W_ih_b = (const float*)d_in[4];
    const float* W_hh_b = (const float*)d_in[5];
    const float* b_b    = (const float*)d_in[6];
    const float* slot_emb = (const float*)d_in[7];
    const int* bio      = (const int*)d_in[8];
    float* out = (float*)d_out;

    char* ws = (char*)d_ws;
    u16*  xg     = (u16*)(ws + 0);              // 4096*8*512 bf16   = 33,554,432
    u16*  wih2   = (u16*)(ws + 33554432);       // 2048*512 bf16     =  2,097,152
    u16*  whh2   = (u16*)(ws + 35651584);       // 2*1024*256 bf16   =  1,048,576
    int*  tok    = (int*)(ws + 36700160);       // 4096*8 i32        =    131,072
    int*  lenb   = (int*)(ws + 36831232);       // 4096 i32          =     16,384
    int*  vrows  = (int*)(ws + 36847616);       // 32768 i32         =    131,072
    int*  sorder = (int*)(ws + 36978688);       // 4096 i32          =     16,384
    int*  counts = (int*)(ws + 36995072);       // pad 256
    u16*  xw     = (u16*)(ws + 36995328);       // 32768*2048 bf16   = 134,217,728
    float* pooled= (float*)(ws + 171213056);    // 4096*512 f32      =  8,388,608 (zeroed)
    // total: 179,601,664 bytes

    build_w2<<<6144, 256, 0, stream>>>(W_ih_f, W_hh_f, W_ih_b, W_hh_b, wih2, whh2);
    pack_spans2<<<64, 512, 0, stream>>>(bio, tok, lenb);
    build_aux<<<1, 256, 0, stream>>>(lenb, vrows, sorder, counts);
    conv_gather<<<32768, 64, 0, stream>>>(lstm_repr, tok, lenb, xg);
    zero_ws<<<2048, 256, 0, stream>>>((uint4*)pooled, 524288);
    xw_gemm<<<dim3(16, 256), 256, 0, stream>>>(xg, wih2, b_f, b_b, vrows, counts, xw);
    lstm_fused3<<<512, 256, 0, stream>>>(whh2, xw, sorder, lenb, pooled);
    scores_mfma<<<64, 256, 0, stream>>>(pooled, slot_emb, out);
}

// Round 7
// 422.608 us; speedup vs baseline: 1.2359x; 1.2359x over previous
//
#include <hip/hip_runtime.h>
#include <hip/hip_bf16.h>
#include <stdint.h>

// Problem constants
#define B_ 64
#define T_ 512
#define H_ 256
#define D_ 512
#define MS_ 64
#define ML_ 8
#define NST_ 64

typedef unsigned short u16;
typedef unsigned int u32;
typedef __bf16 bf8 __attribute__((ext_vector_type(8)));
typedef float f4 __attribute__((ext_vector_type(4)));

__device__ __forceinline__ u16 f2bf(float f) {
    u32 u = __builtin_bit_cast(u32, f);
    u += 0x7fffu + ((u >> 16) & 1u);   // round-to-nearest-even
    return (u16)(u >> 16);
}
__device__ __forceinline__ float bf2f(u16 v) {
    u32 u = ((u32)v) << 16;
    return __builtin_bit_cast(float, u);
}
__device__ __forceinline__ float sigm(float x) { return 1.f / (1.f + __expf(-x)); }

// ---------------- weight packing ----------------
// wih2[2048][512] bf16 : rows 0..1023 = W_ih_f, 1024..2047 = W_ih_b
// whh2[2][1024][256] bf16
__global__ __launch_bounds__(256) void build_w2(const float* __restrict__ wihf,
                                                const float* __restrict__ whhf,
                                                const float* __restrict__ wihb,
                                                const float* __restrict__ whhb,
                                                u16* __restrict__ wih2,
                                                u16* __restrict__ whh2) {
    int i = blockIdx.x * 256 + threadIdx.x;
    if (i < 1048576) {
        int g = i >> 9, k = i & 511;
        float v = (g < 1024) ? wihf[g * 512 + k] : wihb[(g - 1024) * 512 + k];
        wih2[i] = f2bf(v);
    } else if (i < 1572864) {
        int j = i - 1048576;
        int dir = j >> 18;
        int r = j & 262143;
        int g = r >> 8, k = r & 255;
        float v = dir ? whhb[g * 256 + k] : whhf[g * 256 + k];
        whh2[j] = f2bf(v);
    }
}

__global__ __launch_bounds__(256) void zero_ws(uint4* __restrict__ dst, int n4) {
    int i = blockIdx.x * 256 + threadIdx.x;
    if (i < n4) { uint4 z = {0u, 0u, 0u, 0u}; dst[i] = z; }
}

// ---------------- span packing (parallel, 1 block/row, 1 thread/token) -------
__global__ __launch_bounds__(512) void pack_spans2(const int* __restrict__ bio,
                                                   int* __restrict__ tok,
                                                   int* __restrict__ lenb) {
    __shared__ int wsum[8];
    __shared__ int start_s[64];
    __shared__ int len_s[64];
    int b = blockIdx.x;
    int t = threadIdx.x;
    int lane = t & 63, w = t >> 6;
    int v = bio[b * T_ + t];
    int bm = (v == 1);
    int im = (v == 2);
    if (t < 64) len_s[t] = 0;

    int x = bm;
#pragma unroll
    for (int off = 1; off < 64; off <<= 1) {
        int y = __shfl_up(x, off, 64);
        if (lane >= off) x += y;
    }
    if (lane == 63) wsum[w] = x;
    __syncthreads();
    int wof = 0;
    for (int i = 0; i < w; ++i) wof += wsum[i];
    int sid = x + wof - 1;
    int valid = ((bm | im) && sid >= 0) ? 1 : 0;
    __syncthreads();

    x = valid;
#pragma unroll
    for (int off = 1; off < 64; off <<= 1) {
        int y = __shfl_up(x, off, 64);
        if (lane >= off) x += y;
    }
    if (lane == 63) wsum[w] = x;
    __syncthreads();
    wof = 0;
    for (int i = 0; i < w; ++i) wof += wsum[i];
    int cs = x + wof;

    if (bm && sid < MS_) start_s[sid] = cs;
    __syncthreads();

    if (valid && sid < MS_) {
        int rank = cs - start_s[sid];
        if (rank < ML_) {
            tok[(b * MS_ + sid) * ML_ + rank] = t;
            atomicAdd(&len_s[sid], 1);
        }
    }
    __syncthreads();
    if (t < 64) lenb[b * MS_ + t] = len_s[t];
}

// ---------------- aux lists: valid (span,rank) rows + per-step active lists --
// counts[0..7] = active spans at step p; counts[8] = nv (valid xw rows)
__global__ __launch_bounds__(256) void build_aux2(const int* __restrict__ lenb,
                                                  int* __restrict__ vrows,
                                                  int* __restrict__ lists,
                                                  int* __restrict__ counts) {
    __shared__ int wsum[4];
    int tid = threadIdx.x;
    int lane = tid & 63, w = tid >> 6;
    int len[16];
#pragma unroll
    for (int i = 0; i < 16; ++i) len[i] = lenb[tid * 16 + i];

    // valid rows (span*8 + rank for rank < len)
    int cnt = 0;
#pragma unroll
    for (int i = 0; i < 16; ++i) cnt += len[i];
    int x = cnt;
#pragma unroll
    for (int off = 1; off < 64; off <<= 1) {
        int y = __shfl_up(x, off, 64);
        if (lane >= off) x += y;
    }
    if (lane == 63) wsum[w] = x;
    __syncthreads();
    int wof = 0;
    for (int i = 0; i < w; ++i) wof += wsum[i];
    int pos = wof + x - cnt;
#pragma unroll
    for (int i = 0; i < 16; ++i)
        for (int r = 0; r < len[i]; ++r) vrows[pos++] = (tid * 16 + i) * 8 + r;
    if (tid == 255) counts[8] = pos;
    __syncthreads();

    // per-step active lists
    for (int p = 0; p < ML_; ++p) {
        int c = 0;
#pragma unroll
        for (int i = 0; i < 16; ++i) c += (len[i] > p) ? 1 : 0;
        x = c;
#pragma unroll
        for (int off = 1; off < 64; off <<= 1) {
            int y = __shfl_up(x, off, 64);
            if (lane >= off) x += y;
        }
        if (lane == 63) wsum[w] = x;
        __syncthreads();
        wof = 0;
        for (int i = 0; i < w; ++i) wof += wsum[i];
        int p2 = wof + x - c;
#pragma unroll
        for (int i = 0; i < 16; ++i)
            if (len[i] > p) lists[p * 4096 + p2++] = tid * 16 + i;
        if (tid == 255) counts[p] = p2;
        __syncthreads();
    }
}

// Gather-convert used tokens: xg[span*8+rank][512] bf16.
__global__ __launch_bounds__(64) void conv_gather(const float* __restrict__ repr,
                                                  const int* __restrict__ tok,
                                                  const int* __restrict__ lenb,
                                                  u16* __restrict__ xg) {
    int sr = blockIdx.x;
    int span = sr >> 3, rank = sr & 7;
    if (rank >= lenb[span]) return;
    int t = tok[sr];
    int b = span >> 6;
    const float4* src = (const float4*)(repr + (size_t)(b * T_ + t) * D_);
    ushort4* dst = (ushort4*)(xg + (size_t)sr * D_);
    int i = threadIdx.x;
    float4 v0 = src[i * 2], v1 = src[i * 2 + 1];
    ushort4 o0, o1;
    o0.x = f2bf(v0.x); o0.y = f2bf(v0.y); o0.z = f2bf(v0.z); o0.w = f2bf(v0.w);
    o1.x = f2bf(v1.x); o1.y = f2bf(v1.y); o1.z = f2bf(v1.z); o1.w = f2bf(v1.w);
    dst[i * 2] = o0; dst[i * 2 + 1] = o1;
}

// ---------------- input GEMM: xw[sr][2048] = x[sr] @ wih2^T + bias (bf16 out)
__global__ __launch_bounds__(256) void xw_gemm(const u16* __restrict__ xg,
                                               const u16* __restrict__ wih2,
                                               const float* __restrict__ b_f,
                                               const float* __restrict__ b_b,
                                               const int* __restrict__ vrows,
                                               const int* __restrict__ counts,
                                               u16* __restrict__ xw) {
    int nv = counts[8];
    int base = blockIdx.y * 128;
    if (base >= nv) return;
    __shared__ int varr[128];
    __shared__ u16 As[128 * 72];
    __shared__ u16 Bs[128 * 72];
    int tid = threadIdx.x;
    if (tid < 128) varr[tid] = (base + tid < nv) ? vrows[base + tid] : -1;
    __syncthreads();
    int lane = tid & 63, wv = tid >> 6;
    int mr = lane & 15, q = lane >> 4, q8 = q * 8;
    int m0 = (wv >> 1) * 64, n0 = (wv & 1) * 64;
    int bx = blockIdx.x;

    f4 acc[4][4];
    f4 zed = {0.f, 0.f, 0.f, 0.f};
#pragma unroll
    for (int i = 0; i < 4; ++i)
#pragma unroll
        for (int j = 0; j < 4; ++j) acc[i][j] = zed;

    for (int kt = 0; kt < 8; ++kt) {
#pragma unroll
        for (int i = 0; i < 4; ++i) {
            int cch = tid + i * 256;
            int row = cch >> 3, cc = (cch & 7) * 8;
            int vr = varr[row];
            uint4 v = {0u, 0u, 0u, 0u};
            if (vr >= 0) v = *(const uint4*)(xg + (size_t)vr * 512 + kt * 64 + cc);
            *(uint4*)&As[row * 72 + cc] = v;
            uint4 wv4 = *(const uint4*)(wih2 + (size_t)(bx * 128 + row) * 512 + kt * 64 + cc);
            *(uint4*)&Bs[row * 72 + cc] = wv4;
        }
        __syncthreads();
#pragma unroll
        for (int kk = 0; kk < 64; kk += 32) {
            bf8 af[4], bgv[4];
#pragma unroll
            for (int i = 0; i < 4; ++i) af[i] = *(const bf8*)&As[(m0 + i * 16 + mr) * 72 + kk + q8];
#pragma unroll
            for (int j = 0; j < 4; ++j) bgv[j] = *(const bf8*)&Bs[(n0 + j * 16 + mr) * 72 + kk + q8];
#pragma unroll
            for (int i = 0; i < 4; ++i)
#pragma unroll
                for (int j = 0; j < 4; ++j)
                    acc[i][j] = __builtin_amdgcn_mfma_f32_16x16x32_bf16(af[i], bgv[j], acc[i][j], 0, 0, 0);
        }
        __syncthreads();
    }
#pragma unroll
    for (int j = 0; j < 4; ++j) {
        int n = bx * 128 + n0 + j * 16 + mr;
        float bias = (n < 1024) ? b_f[n] : b_b[n - 1024];
#pragma unroll
        for (int i = 0; i < 4; ++i)
#pragma unroll
            for (int r = 0; r < 4; ++r) {
                int m = m0 + i * 16 + q * 4 + r;
                int vr = varr[m];
                if (vr >= 0) xw[(size_t)vr * 2048 + n] = f2bf(acc[i][j][r] + bias);
            }
    }
}

// ---------------- LSTM step: GEMM + fused cell epilogue ----------------
// Grid (hb=4, span-block=64, dir=2). Block: M=64 active spans, K=256 (h),
// N=256 gates = 4 gate-types x 64-hidden chunk (hb). C-layout puts I,F,G,O
// of one (span,hidden) in-lane -> cell math in epilogue, no gates buffer.
// h double-buffered across launches (hread/hwrite parity), c f32 in global.
__global__ __launch_bounds__(256) void lstm_step(const u16* __restrict__ whh2,
                                                 const u16* __restrict__ xw,
                                                 const u16* __restrict__ hread,
                                                 u16* __restrict__ hwrite,
                                                 float* __restrict__ cst,
                                                 float* __restrict__ pooled,
                                                 const int* __restrict__ lists,
                                                 const int* __restrict__ counts,
                                                 const int* __restrict__ lenb,
                                                 int p) {
    int cnt = counts[p];
    int base = blockIdx.y * 64;
    if (base >= cnt) return;
    int hb = blockIdx.x;
    int dir = blockIdx.z;

    __shared__ u16 As[64 * 72];
    __shared__ u16 Bs[256 * 72];
    __shared__ int sp_s[64], ln_s[64];
    int tid = threadIdx.x;
    if (tid < 64) {
        int s = -1, l = 0;
        if (base + tid < cnt) { s = lists[p * 4096 + base + tid]; l = lenb[s]; }
        sp_s[tid] = s; ln_s[tid] = l;
    }
    __syncthreads();

    int lane = tid & 63, wv = tid >> 6;
    int mr = lane & 15, q = lane >> 4, q8 = q * 8;
    int w16 = wv * 16;
    const u16* wbase = whh2 + (size_t)dir * 262144;

    f4 acc[4][4];            // [gate-type][n-subtile]
    f4 zed = {0.f, 0.f, 0.f, 0.f};
#pragma unroll
    for (int i = 0; i < 4; ++i)
#pragma unroll
        for (int j = 0; j < 4; ++j) acc[i][j] = zed;

    for (int kt = 0; kt < 4; ++kt) {
        // stage A: h rows of 64 spans, k-chunk 64 (512 x 16B, 2/thread)
#pragma unroll
        for (int i = 0; i < 2; ++i) {
            int cch = tid + i * 256;
            int row = cch >> 3, cc = (cch & 7) * 8;
            int s = sp_s[row];
            uint4 v = {0u, 0u, 0u, 0u};
            if (s >= 0) v = *(const uint4*)(hread + ((size_t)dir * 4096 + s) * 256 + kt * 64 + cc);
            *(uint4*)&As[row * 72 + cc] = v;
        }
        // stage B: 256 W rows (4 gate-types x 64-hid chunk), k-chunk 64 (8/thread)
#pragma unroll
        for (int i = 0; i < 8; ++i) {
            int cch = tid + i * 256;
            int row = cch >> 3, cc = (cch & 7) * 8;
            int wrow = (row >> 6) * 256 + hb * 64 + (row & 63);
            uint4 v = *(const uint4*)(wbase + (size_t)wrow * 256 + kt * 64 + cc);
            *(uint4*)&Bs[row * 72 + cc] = v;
        }
        __syncthreads();
#pragma unroll
        for (int kk = 0; kk < 64; kk += 32) {
            bf8 af = *(const bf8*)&As[(w16 + mr) * 72 + kk + q8];
#pragma unroll
            for (int gt = 0; gt < 4; ++gt)
#pragma unroll
                for (int ns = 0; ns < 4; ++ns) {
                    bf8 bg = *(const bf8*)&Bs[(gt * 64 + ns * 16 + mr) * 72 + kk + q8];
                    acc[gt][ns] = __builtin_amdgcn_mfma_f32_16x16x32_bf16(af, bg, acc[gt][ns], 0, 0, 0);
                }
        }
        __syncthreads();
    }

    // epilogue: cell update. lane holds I,F,G,O for span m = w16+q*4+r,
    // hid = hb*64 + ns*16 + mr.
#pragma unroll
    for (int ns = 0; ns < 4; ++ns)
#pragma unroll
        for (int r = 0; r < 4; ++r) {
            int m = w16 + q * 4 + r;
            int s = sp_s[m];
            if (s < 0) continue;
            int len = ln_s[m];
            int rk = dir ? (len - 1 - p) : p;
            int hid = hb * 64 + ns * 16 + mr;
            const u16* xr = xw + ((size_t)s * 8 + rk) * 2048 + dir * 1024 + hid;
            float I = acc[0][ns][r] + bf2f(xr[0]);
            float F = acc[1][ns][r] + bf2f(xr[256]);
            float G = acc[2][ns][r] + bf2f(xr[512]);
            float O = acc[3][ns][r] + bf2f(xr[768]);
            size_t ci = ((size_t)dir * 4096 + s) * 256 + hid;
            float c0 = cst[ci];
            float cn = sigm(F) * c0 + sigm(I) * tanhf(G);
            cst[ci] = cn;
            float h = sigm(O) * tanhf(cn);
            hwrite[ci] = f2bf(h);
            pooled[(size_t)s * 512 + dir * 256 + hid] += h;
        }
}

// ---------------- final scores: MFMA GEMM [4096x512] x [512x64] ----------------
__global__ __launch_bounds__(256) void scores_mfma(const float* __restrict__ pooled,
                                                   const float* __restrict__ emb,
                                                   float* __restrict__ out) {
    int g = blockIdx.x;
    int tid = threadIdx.x;
    __shared__ u16 As[64 * 72];
    __shared__ u16 Bs[64 * 72];
    int lane = tid & 63;
    int w16 = (tid >> 6) * 16;
    int mr = lane & 15;
    int q = lane >> 4;
    int q8 = q * 8;

    f4 acc[4];
    f4 zed = {0.f, 0.f, 0.f, 0.f};
#pragma unroll
    for (int i = 0; i < 4; ++i) acc[i] = zed;

    for (int kt = 0; kt < 8; ++kt) {
#pragma unroll
        for (int i = 0; i < 2; ++i) {
            int cch = tid + i * 256;
            int row = cch >> 3;
            int cc = (cch & 7) * 8;
            const float4* a = (const float4*)(pooled + (size_t)(g * 64 + row) * 512 + kt * 64 + cc);
            float4 v0 = a[0], v1 = a[1];
            ushort4 o0, o1;
            o0.x = f2bf(v0.x); o0.y = f2bf(v0.y); o0.z = f2bf(v0.z); o0.w = f2bf(v0.w);
            o1.x = f2bf(v1.x); o1.y = f2bf(v1.y); o1.z = f2bf(v1.z); o1.w = f2bf(v1.w);
            *(ushort4*)&As[row * 72 + cc] = o0;
            *(ushort4*)&As[row * 72 + cc + 4] = o1;
            const float4* b = (const float4*)(emb + (size_t)row * 512 + kt * 64 + cc);
            float4 w0 = b[0], w1 = b[1];
            ushort4 p0, p1;
            p0.x = f2bf(w0.x); p0.y = f2bf(w0.y); p0.z = f2bf(w0.z); p0.w = f2bf(w0.w);
            p1.x = f2bf(w1.x); p1.y = f2bf(w1.y); p1.z = f2bf(w1.z); p1.w = f2bf(w1.w);
            *(ushort4*)&Bs[row * 72 + cc] = p0;
            *(ushort4*)&Bs[row * 72 + cc + 4] = p1;
        }
        __syncthreads();
#pragma unroll
        for (int kk = 0; kk < 64; kk += 32) {
            bf8 af = *(const bf8*)&As[(w16 + mr) * 72 + kk + q8];
#pragma unroll
            for (int nt = 0; nt < 4; ++nt) {
                bf8 bgv = *(const bf8*)&Bs[(nt * 16 + mr) * 72 + kk + q8];
                acc[nt] = __builtin_amdgcn_mfma_f32_16x16x32_bf16(af, bgv, acc[nt], 0, 0, 0);
            }
        }
        __syncthreads();
    }
#pragma unroll
    for (int nt = 0; nt < 4; ++nt)
#pragma unroll
        for (int r = 0; r < 4; ++r) {
            int m = g * 64 + w16 + q * 4 + r;
            int n = nt * 16 + mr;
            out[(size_t)m * 64 + n] = acc[nt][r];
        }
}

// ---------------- launch ----------------

extern "C" void kernel_launch(void* const* d_in, const int* in_sizes, int n_in,
                              void* d_out, int out_size, void* d_ws, size_t ws_size,
                              hipStream_t stream) {
    const float* lstm_repr = (const float*)d_in[0];
    const float* W_ih_f = (const float*)d_in[1];
    const float* W_hh_f = (const float*)d_in[2];
    const float* b_f    = (const float*)d_in[3];
    const float* W_ih_b = (const float*)d_in[4];
    const float* W_hh_b = (const float*)d_in[5];
    const float* b_b    = (const float*)d_in[6];
    const float* slot_emb = (const float*)d_in[7];
    const int* bio      = (const int*)d_in[8];
    float* out = (float*)d_out;

    char* ws = (char*)d_ws;
    u16*  xg     = (u16*)(ws + 0);              // 4096*8*512 bf16   = 33,554,432
    u16*  wih2   = (u16*)(ws + 33554432);       // 2048*512 bf16     =  2,097,152
    u16*  whh2   = (u16*)(ws + 35651584);       // 2*1024*256 bf16   =  1,048,576
    int*  tok    = (int*)(ws + 36700160);       // 4096*8 i32        =    131,072
    int*  lenb   = (int*)(ws + 36831232);       // 4096 i32          =     16,384
    int*  vrows  = (int*)(ws + 36847616);       // 32768 i32         =    131,072
    int*  lists  = (int*)(ws + 36978688);       // 8*4096 i32        =    131,072
    int*  counts = (int*)(ws + 37109760);       // 9 i32 (pad 256)
    u16*  xw     = (u16*)(ws + 37110016);       // 32768*2048 bf16   = 134,217,728
    u16*  hbuf   = (u16*)(ws + 171327744);      // 2par*2dir*4096*256 bf16 = 8,388,608 (zeroed)
    float* cst   = (float*)(ws + 179716352);    // 2*4096*256 f32    =  8,388,608 (zeroed)
    float* pooled= (float*)(ws + 188104960);    // 4096*512 f32      =  8,388,608 (zeroed)
    // total: 196,493,568 bytes

    build_w2<<<6144, 256, 0, stream>>>(W_ih_f, W_hh_f, W_ih_b, W_hh_b, wih2, whh2);
    pack_spans2<<<64, 512, 0, stream>>>(bio, tok, lenb);
    build_aux2<<<1, 256, 0, stream>>>(lenb, vrows, lists, counts);
    conv_gather<<<32768, 64, 0, stream>>>(lstm_repr, tok, lenb, xg);
    // zero hbuf + cst + pooled (contiguous 25,165,824 B = 1,572,864 uint4)
    zero_ws<<<6144, 256, 0, stream>>>((uint4*)hbuf, 1572864);
    xw_gemm<<<dim3(16, 256), 256, 0, stream>>>(xg, wih2, b_f, b_b, vrows, counts, xw);

    const size_t HPAR = (size_t)2 * 4096 * 256;   // elements per parity
    for (int p = 0; p < 8; ++p) {
        u16* hr = hbuf + (size_t)(p & 1) * HPAR;
        u16* hw = hbuf + (size_t)((p & 1) ^ 1) * HPAR;
        lstm_step<<<dim3(4, 64, 2), 256, 0, stream>>>(whh2, xw, hr, hw, cst, pooled,
                                                      lists, counts, lenb, p);
    }
    scores_mfma<<<64, 256, 0, stream>>>(pooled, slot_emb, out);
}